// Round 1
// baseline (1199.765 us; speedup 1.0000x reference)
//
#include <hip/hip_runtime.h>
#include <hip/hip_fp16.h>

#define BB 128
#define NN 512
#define HH 128
#define TT 4

typedef _Float16 f16;
typedef _Float16 half8 __attribute__((ext_vector_type(8)));
typedef float floatx4 __attribute__((ext_vector_type(4)));

// fp32 -> f16 hi/lo split: x ~= hi + lo, |lo| <= |x|*2^-11
__device__ __forceinline__ void split1(float x, f16& hi, f16& lo) {
  hi = (f16)x;
  lo = (f16)(x - (float)hi);
}

// ---------- one-time prep ----------

// six HxH fp32 weights, pre-scaled x16, split into f16 hi/lo
__global__ void k_wsplit(const float* __restrict__ wz, const float* __restrict__ uz,
                         const float* __restrict__ wr, const float* __restrict__ ur,
                         const float* __restrict__ wc, const float* __restrict__ uc,
                         f16* __restrict__ whi, f16* __restrict__ wlo) {
  int mat = blockIdx.x >> 6;
  int idx = ((blockIdx.x & 63) << 8) + threadIdx.x;
  const float* src = mat==0?wz : mat==1?uz : mat==2?wr : mat==3?ur : mat==4?wc : uc;
  float v = src[idx] * 16.0f;
  f16 hi, lo; split1(v, hi, lo);
  whi[mat*16384 + idx] = hi;
  wlo[mat*16384 + idx] = lo;
}

// summed gate biases: [0]=b_wz+b_uz, [1]=b_wr+b_ur, [2]=b_w+b_u
__global__ void k_bsum(const float* __restrict__ bwz, const float* __restrict__ buz,
                       const float* __restrict__ bwr, const float* __restrict__ bur,
                       const float* __restrict__ bw,  const float* __restrict__ bu,
                       float* __restrict__ bias3) {
  int b = blockIdx.x, j = threadIdx.x;
  bias3[b*HH + j] = b==0 ? bwz[j]+buz[j] : (b==1 ? bwr[j]+bur[j] : bw[j]+bu[j]);
}

__global__ void k_copy_h0(const float* __restrict__ hin, float* __restrict__ h) {
  int v = blockIdx.x * 256 + threadIdx.x;
  ((float4*)h)[v] = ((const float4*)hin)[v];
}

// ---------- per-step kernels ----------

// a32[b][n][j] = b_ah[j] + sum_m A[b][m][n] * h[b][m][j], fp32-accurate via
// hi/lo split f16 MFMA (3 passes). In-kernel transpose staging, XOR-swizzled.
// grid (4 n-tiles, 128 batch), 256 thr (4 waves), tile 128x128, BK=64.
__global__ __launch_bounds__(256) void k_biggemm(const float* __restrict__ A,
                                                 const float* __restrict__ h,
                                                 const float* __restrict__ b_ah,
                                                 float* __restrict__ a32) {
  __shared__ __align__(16) f16 Ah[128*64], Al[128*64], Hh[128*64], Hl[128*64];
  const int b = blockIdx.y, n0 = blockIdx.x * 128, tid = threadIdx.x;
  const int w = tid >> 6, L = tid & 63, quad = L >> 4, l16 = L & 15;
  const int rowsel = tid >> 5, colsel = tid & 31;
  const float* Ab = A + (size_t)b * NN * NN;
  const float* hb = h + (size_t)b * NN * HH;
  const floatx4 zero = {0.f, 0.f, 0.f, 0.f};
  floatx4 acc[2][8];
  for (int sr = 0; sr < 2; sr++) for (int sc = 0; sc < 8; sc++) acc[sr][sc] = zero;

  for (int mc = 0; mc < NN; mc += 64) {
    float4 va[8], vh[8];
#pragma unroll
    for (int i = 0; i < 8; i++) {
      int mm = rowsel * 8 + i;
      va[i] = *(const float4*)(Ab + (size_t)(mc + mm) * NN + n0 + colsel * 4);
      vh[i] = *(const float4*)(hb + (size_t)(mc + mm) * HH + colsel * 4);
    }
#pragma unroll
    for (int q = 0; q < 4; q++) {
      int c = colsel * 4 + q;
      half8 avh, avl, hvh, hvl;
#pragma unroll
      for (int i = 0; i < 8; i++) {
        f16 hi, lo;
        split1(((const float*)&va[i])[q], hi, lo); avh[i] = hi; avl[i] = lo;
        split1(((const float*)&vh[i])[q], hi, lo); hvh[i] = hi; hvl[i] = lo;
      }
      int blk = (rowsel ^ (c & 7)) * 8;
      *(half8*)&Ah[c*64 + blk] = avh;  *(half8*)&Al[c*64 + blk] = avl;
      *(half8*)&Hh[c*64 + blk] = hvh;  *(half8*)&Hl[c*64 + blk] = hvl;
    }
    __syncthreads();
#pragma unroll
    for (int ks = 0; ks < 2; ks++) {
      const int kb = ks * 4 + quad;
      half8 afh[2], afl[2], bfh[8], bfl[8];
      for (int sr = 0; sr < 2; sr++) {
        int c = w*32 + sr*16 + l16, o = c*64 + ((kb ^ (c & 7)) * 8);
        afh[sr] = *(const half8*)&Ah[o];
        afl[sr] = *(const half8*)&Al[o];
      }
      for (int sc = 0; sc < 8; sc++) {
        int c = sc*16 + l16, o = c*64 + ((kb ^ (c & 7)) * 8);
        bfh[sc] = *(const half8*)&Hh[o];
        bfl[sc] = *(const half8*)&Hl[o];
      }
      for (int sr = 0; sr < 2; sr++)
        for (int sc = 0; sc < 8; sc++) {
          acc[sr][sc] = __builtin_amdgcn_mfma_f32_16x16x32_f16(afh[sr], bfh[sc], acc[sr][sc], 0, 0, 0);
          acc[sr][sc] = __builtin_amdgcn_mfma_f32_16x16x32_f16(afh[sr], bfl[sc], acc[sr][sc], 0, 0, 0);
          acc[sr][sc] = __builtin_amdgcn_mfma_f32_16x16x32_f16(afl[sr], bfh[sc], acc[sr][sc], 0, 0, 0);
        }
    }
    __syncthreads();
  }
  float bah[8];
  for (int sc = 0; sc < 8; sc++) bah[sc] = b_ah[sc*16 + l16];
  float* ab = a32 + (size_t)b * NN * HH;
#pragma unroll
  for (int sr = 0; sr < 2; sr++)
    for (int rg = 0; rg < 4; rg++) {
      const int row = n0 + w*32 + sr*16 + quad*4 + rg;   // C/D: row=quad*4+reg
      for (int sc = 0; sc < 8; sc++)
        ab[(size_t)row*HH + sc*16 + l16] = acc[sr][sc][rg] + bah[sc];  // col=lane&15
    }
}

// gates, 64 rows of [B*N] per block (1024 blocks), 256 thr = 4 waves,
// each wave owns 16 rows. All GEMMs hi/lo-split f16 MFMA (3 passes),
// weights pre-scaled x16 (epilogue /16). h fp32 in d_out; a fp32 in ws.
// Sweeps: r -> (rh to per-wave LDS hi/lo, no barrier) -> c -> z -> h update.
// LDS 34.8 KB -> 4 blocks/CU by LDS; VGPR-capped at 3 waves/SIMD (12 waves/CU).
__global__ __launch_bounds__(256, 3) void k_gates(const float* __restrict__ a32,
                                                  float* __restrict__ h,
                                                  const f16* __restrict__ whi,
                                                  const f16* __restrict__ wlo,
                                                  const float* __restrict__ bias3) {
  __shared__ __align__(16) f16 rhh[64*136], rhl[64*136];
  const int row0 = blockIdx.x << 6, tid = threadIdx.x;
  const int w = tid >> 6, L = tid & 63, quad = L >> 4, l16 = L & 15;
  const int wb = w << 4;                     // wave's 16-row base within block
  const float* ap = a32 + (size_t)(row0 + wb + l16) * HH;
  const float* hp = h + (size_t)(row0 + wb + l16) * HH;
  // a fragments (live across all sweeps): A-op layout m=lane&15, k=quad*8+j
  half8 afh[4], afl[4];
#pragma unroll
  for (int ks = 0; ks < 4; ks++) {
    const int ko = ks*32 + quad*8;
    float4 p = *(const float4*)(ap + ko);
    float4 q2 = *(const float4*)(ap + ko + 4);
    const float* v = (const float*)&p;
    const float* v2 = (const float*)&q2;
    for (int i = 0; i < 4; i++) { f16 hi, lo; split1(v[i],  hi, lo); afh[ks][i]   = hi; afl[ks][i]   = lo; }
    for (int i = 0; i < 4; i++) { f16 hi, lo; split1(v2[i], hi, lo); afh[ks][i+4] = hi; afl[ks][i+4] = lo; }
  }
  const floatx4 zero = {0.f, 0.f, 0.f, 0.f};
  const f16* Wz_h = whi;            const f16* Wz_l = wlo;
  const f16* Uz_h = whi + 16384;    const f16* Uz_l = wlo + 16384;
  const f16* Wr_h = whi + 2*16384;  const f16* Wr_l = wlo + 2*16384;
  const f16* Ur_h = whi + 3*16384;  const f16* Ur_l = wlo + 3*16384;
  const f16* Wc_h = whi + 4*16384;  const f16* Wc_l = wlo + 4*16384;
  const f16* Uc_h = whi + 5*16384;  const f16* Uc_l = wlo + 5*16384;

  // ---- r sweep ----
  floatx4 racc[8];
  for (int sc = 0; sc < 8; sc++) racc[sc] = zero;
#pragma unroll
  for (int ks = 0; ks < 4; ks++) {
    const int ko = ks*32 + quad*8;
    half8 hfh, hfl;
    {
      float4 p = *(const float4*)(hp + ko);
      float4 q2 = *(const float4*)(hp + ko + 4);
      const float* v = (const float*)&p; const float* v2 = (const float*)&q2;
      for (int i = 0; i < 4; i++) { f16 hi, lo; split1(v[i],  hi, lo); hfh[i]   = hi; hfl[i]   = lo; }
      for (int i = 0; i < 4; i++) { f16 hi, lo; split1(v2[i], hi, lo); hfh[i+4] = hi; hfl[i+4] = lo; }
    }
#pragma unroll
    for (int sc = 0; sc < 8; sc++) {
      const int wo = (sc*16 + l16)*HH + ko;      // B-op: n=lane&15 row of W, k-contig
      half8 wh = *(const half8*)(Wr_h + wo), wl = *(const half8*)(Wr_l + wo);
      half8 uh = *(const half8*)(Ur_h + wo), ul = *(const half8*)(Ur_l + wo);
      racc[sc] = __builtin_amdgcn_mfma_f32_16x16x32_f16(afh[ks], wh, racc[sc], 0, 0, 0);
      racc[sc] = __builtin_amdgcn_mfma_f32_16x16x32_f16(afh[ks], wl, racc[sc], 0, 0, 0);
      racc[sc] = __builtin_amdgcn_mfma_f32_16x16x32_f16(afl[ks], wh, racc[sc], 0, 0, 0);
      racc[sc] = __builtin_amdgcn_mfma_f32_16x16x32_f16(hfh, uh, racc[sc], 0, 0, 0);
      racc[sc] = __builtin_amdgcn_mfma_f32_16x16x32_f16(hfh, ul, racc[sc], 0, 0, 0);
      racc[sc] = __builtin_amdgcn_mfma_f32_16x16x32_f16(hfl, uh, racc[sc], 0, 0, 0);
    }
  }
  // epilogue r: rh = sigmoid(pr)*h -> per-wave LDS region (C/D row=quad*4+reg)
  {
    float brv[8];
    for (int sc = 0; sc < 8; sc++) brv[sc] = bias3[128 + sc*16 + l16];
#pragma unroll
    for (int rg = 0; rg < 4; rg++) {
      const int lrow = wb + quad*4 + rg;
      const float* hrow = h + (size_t)(row0 + lrow)*HH;
      for (int sc = 0; sc < 8; sc++) {
        const int col = sc*16 + l16;
        float pr = racc[sc][rg] * 0.0625f + brv[sc];
        float rv = 1.f / (1.f + expf(-pr));
        float rhv = rv * hrow[col];
        f16 hi, lo; split1(rhv, hi, lo);
        rhh[lrow*136 + col] = hi;
        rhl[lrow*136 + col] = lo;
      }
    }
  }
  // wave-private LDS region: no __syncthreads needed, just drain LDS writes
  asm volatile("s_waitcnt lgkmcnt(0)" ::: "memory");

  // ---- c sweep: a@Wc^T + rh@Uc^T ----
  floatx4 cacc[8];
  for (int sc = 0; sc < 8; sc++) cacc[sc] = zero;
#pragma unroll
  for (int ks = 0; ks < 4; ks++) {
    const int ko = ks*32 + quad*8;
    const int o = (wb + l16)*136 + ko;
    half8 rfh = *(const half8*)&rhh[o];
    half8 rfl = *(const half8*)&rhl[o];
#pragma unroll
    for (int sc = 0; sc < 8; sc++) {
      const int wo = (sc*16 + l16)*HH + ko;
      half8 wh = *(const half8*)(Wc_h + wo), wl = *(const half8*)(Wc_l + wo);
      half8 uh = *(const half8*)(Uc_h + wo), ul = *(const half8*)(Uc_l + wo);
      cacc[sc] = __builtin_amdgcn_mfma_f32_16x16x32_f16(afh[ks], wh, cacc[sc], 0, 0, 0);
      cacc[sc] = __builtin_amdgcn_mfma_f32_16x16x32_f16(afh[ks], wl, cacc[sc], 0, 0, 0);
      cacc[sc] = __builtin_amdgcn_mfma_f32_16x16x32_f16(afl[ks], wh, cacc[sc], 0, 0, 0);
      cacc[sc] = __builtin_amdgcn_mfma_f32_16x16x32_f16(rfh, uh, cacc[sc], 0, 0, 0);
      cacc[sc] = __builtin_amdgcn_mfma_f32_16x16x32_f16(rfh, ul, cacc[sc], 0, 0, 0);
      cacc[sc] = __builtin_amdgcn_mfma_f32_16x16x32_f16(rfl, uh, cacc[sc], 0, 0, 0);
    }
  }
  // ---- z sweep: a@Wz^T + h@Uz^T ----
  floatx4 zacc[8];
  for (int sc = 0; sc < 8; sc++) zacc[sc] = zero;
#pragma unroll
  for (int ks = 0; ks < 4; ks++) {
    const int ko = ks*32 + quad*8;
    half8 hfh, hfl;
    {
      float4 p = *(const float4*)(hp + ko);
      float4 q2 = *(const float4*)(hp + ko + 4);
      const float* v = (const float*)&p; const float* v2 = (const float*)&q2;
      for (int i = 0; i < 4; i++) { f16 hi, lo; split1(v[i],  hi, lo); hfh[i]   = hi; hfl[i]   = lo; }
      for (int i = 0; i < 4; i++) { f16 hi, lo; split1(v2[i], hi, lo); hfh[i+4] = hi; hfl[i+4] = lo; }
    }
#pragma unroll
    for (int sc = 0; sc < 8; sc++) {
      const int wo = (sc*16 + l16)*HH + ko;
      half8 wh = *(const half8*)(Wz_h + wo), wl = *(const half8*)(Wz_l + wo);
      half8 uh = *(const half8*)(Uz_h + wo), ul = *(const half8*)(Uz_l + wo);
      zacc[sc] = __builtin_amdgcn_mfma_f32_16x16x32_f16(afh[ks], wh, zacc[sc], 0, 0, 0);
      zacc[sc] = __builtin_amdgcn_mfma_f32_16x16x32_f16(afh[ks], wl, zacc[sc], 0, 0, 0);
      zacc[sc] = __builtin_amdgcn_mfma_f32_16x16x32_f16(afl[ks], wh, zacc[sc], 0, 0, 0);
      zacc[sc] = __builtin_amdgcn_mfma_f32_16x16x32_f16(hfh, uh, zacc[sc], 0, 0, 0);
      zacc[sc] = __builtin_amdgcn_mfma_f32_16x16x32_f16(hfh, ul, zacc[sc], 0, 0, 0);
      zacc[sc] = __builtin_amdgcn_mfma_f32_16x16x32_f16(hfl, uh, zacc[sc], 0, 0, 0);
    }
  }
  // ---- final epilogue ----
  float bzv[8], bcv[8];
  for (int sc = 0; sc < 8; sc++) {
    bzv[sc] = bias3[sc*16 + l16];
    bcv[sc] = bias3[256 + sc*16 + l16];
  }
#pragma unroll
  for (int rg = 0; rg < 4; rg++) {
    const int lrow = wb + quad*4 + rg;
    float* hrow = h + (size_t)(row0 + lrow)*HH;
    for (int sc = 0; sc < 8; sc++) {
      const int col = sc*16 + l16;
      float pz = zacc[sc][rg] * 0.0625f + bzv[sc];
      float zv = 1.f / (1.f + expf(-pz));
      float cv = tanhf(cacc[sc][rg] * 0.0625f + bcv[sc]);
      float hv = hrow[col];
      hrow[col] = hv + zv*(cv - hv);   // (1-z)h + z*c
    }
  }
}

extern "C" void kernel_launch(void* const* d_in, const int* in_sizes, int n_in,
                              void* d_out, int out_size, void* d_ws, size_t ws_size,
                              hipStream_t stream) {
  const float* A      = (const float*)d_in[0];
  const float* hidden = (const float*)d_in[1];
  const float* b_ah   = (const float*)d_in[2];
  const float* w_z = (const float*)d_in[3];  const float* b_wz = (const float*)d_in[4];
  const float* u_z = (const float*)d_in[5];  const float* b_uz = (const float*)d_in[6];
  const float* w_r = (const float*)d_in[7];  const float* b_wr = (const float*)d_in[8];
  const float* u_r = (const float*)d_in[9];  const float* b_ur = (const float*)d_in[10];
  const float* w   = (const float*)d_in[11]; const float* b_w  = (const float*)d_in[12];
  const float* u   = (const float*)d_in[13]; const float* b_u  = (const float*)d_in[14];

  float* h = (float*)d_out;                       // fp32 h state == output [B,N,H]
  char* ws = (char*)d_ws;
  float* a32  = (float*)ws;                       // 33,554,432 B
  f16*   whi  = (f16*)(ws + 33554432);            // 196,608 B
  f16*   wlo  = (f16*)(ws + 33751040);            // 196,608 B
  float* bias3= (float*)(ws + 33947648);          // 1,536 B   (total ~33.9 MB)

  k_wsplit<<<384, 256, 0, stream>>>(w_z, u_z, w_r, u_r, w, u, whi, wlo);
  k_bsum<<<3, HH, 0, stream>>>(b_wz, b_uz, b_wr, b_ur, b_w, b_u, bias3);
  k_copy_h0<<<8192, 256, 0, stream>>>(hidden, h);

  for (int t = 0; t < TT; t++) {
    k_biggemm<<<dim3(4, BB), 256, 0, stream>>>(A, h, b_ah, a32);
    k_gates<<<1024, 256, 0, stream>>>(a32, h, whi, wlo, bias3);
  }
}

// Round 2
// 992.648 us; speedup vs baseline: 1.2087x; 1.2087x over previous
//
#include <hip/hip_runtime.h>
#include <hip/hip_fp16.h>

#define BB 128
#define NN 512
#define HH 128
#define TT 4

typedef _Float16 f16;
typedef _Float16 half8 __attribute__((ext_vector_type(8)));
typedef float floatx4 __attribute__((ext_vector_type(4)));

// fp32 -> f16 hi/lo split: x ~= hi + lo, |lo| <= |x|*2^-11
__device__ __forceinline__ void split1(float x, f16& hi, f16& lo) {
  hi = (f16)x;
  lo = (f16)(x - (float)hi);
}

// ---------- one-time prep ----------

// six HxH fp32 weights, pre-scaled x16, split into f16 hi/lo
__global__ void k_wsplit(const float* __restrict__ wz, const float* __restrict__ uz,
                         const float* __restrict__ wr, const float* __restrict__ ur,
                         const float* __restrict__ wc, const float* __restrict__ uc,
                         f16* __restrict__ whi, f16* __restrict__ wlo) {
  int mat = blockIdx.x >> 6;
  int idx = ((blockIdx.x & 63) << 8) + threadIdx.x;
  const float* src = mat==0?wz : mat==1?uz : mat==2?wr : mat==3?ur : mat==4?wc : uc;
  float v = src[idx] * 16.0f;
  f16 hi, lo; split1(v, hi, lo);
  whi[mat*16384 + idx] = hi;
  wlo[mat*16384 + idx] = lo;
}

// summed gate biases: [0]=b_wz+b_uz, [1]=b_wr+b_ur, [2]=b_w+b_u
__global__ void k_bsum(const float* __restrict__ bwz, const float* __restrict__ buz,
                       const float* __restrict__ bwr, const float* __restrict__ bur,
                       const float* __restrict__ bw,  const float* __restrict__ bu,
                       float* __restrict__ bias3) {
  int b = blockIdx.x, j = threadIdx.x;
  bias3[b*HH + j] = b==0 ? bwz[j]+buz[j] : (b==1 ? bwr[j]+bur[j] : bw[j]+bu[j]);
}

__global__ void k_copy_h0(const float* __restrict__ hin, float* __restrict__ h) {
  int v = blockIdx.x * 256 + threadIdx.x;
  ((float4*)h)[v] = ((const float4*)hin)[v];
}

// ---------- per-step kernels ----------

// a32[b][n][j] = b_ah[j] + sum_m A[b][m][n] * h[b][m][j], fp32-accurate via
// hi/lo split f16 MFMA (3 passes). In-kernel transpose staging, XOR-swizzled.
// grid (4 n-tiles, 128 batch), 256 thr (4 waves), tile 128x128, BK=64.
__global__ __launch_bounds__(256) void k_biggemm(const float* __restrict__ A,
                                                 const float* __restrict__ h,
                                                 const float* __restrict__ b_ah,
                                                 float* __restrict__ a32) {
  __shared__ __align__(16) f16 Ah[128*64], Al[128*64], Hh[128*64], Hl[128*64];
  const int b = blockIdx.y, n0 = blockIdx.x * 128, tid = threadIdx.x;
  const int w = tid >> 6, L = tid & 63, quad = L >> 4, l16 = L & 15;
  const int rowsel = tid >> 5, colsel = tid & 31;
  const float* Ab = A + (size_t)b * NN * NN;
  const float* hb = h + (size_t)b * NN * HH;
  const floatx4 zero = {0.f, 0.f, 0.f, 0.f};
  floatx4 acc[2][8];
  for (int sr = 0; sr < 2; sr++) for (int sc = 0; sc < 8; sc++) acc[sr][sc] = zero;

  for (int mc = 0; mc < NN; mc += 64) {
    float4 va[8], vh[8];
#pragma unroll
    for (int i = 0; i < 8; i++) {
      int mm = rowsel * 8 + i;
      va[i] = *(const float4*)(Ab + (size_t)(mc + mm) * NN + n0 + colsel * 4);
      vh[i] = *(const float4*)(hb + (size_t)(mc + mm) * HH + colsel * 4);
    }
#pragma unroll
    for (int q = 0; q < 4; q++) {
      int c = colsel * 4 + q;
      half8 avh, avl, hvh, hvl;
#pragma unroll
      for (int i = 0; i < 8; i++) {
        f16 hi, lo;
        split1(((const float*)&va[i])[q], hi, lo); avh[i] = hi; avl[i] = lo;
        split1(((const float*)&vh[i])[q], hi, lo); hvh[i] = hi; hvl[i] = lo;
      }
      int blk = (rowsel ^ (c & 7)) * 8;
      *(half8*)&Ah[c*64 + blk] = avh;  *(half8*)&Al[c*64 + blk] = avl;
      *(half8*)&Hh[c*64 + blk] = hvh;  *(half8*)&Hl[c*64 + blk] = hvl;
    }
    __syncthreads();
#pragma unroll
    for (int ks = 0; ks < 2; ks++) {
      const int kb = ks * 4 + quad;
      half8 afh[2], afl[2], bfh[8], bfl[8];
      for (int sr = 0; sr < 2; sr++) {
        int c = w*32 + sr*16 + l16, o = c*64 + ((kb ^ (c & 7)) * 8);
        afh[sr] = *(const half8*)&Ah[o];
        afl[sr] = *(const half8*)&Al[o];
      }
      for (int sc = 0; sc < 8; sc++) {
        int c = sc*16 + l16, o = c*64 + ((kb ^ (c & 7)) * 8);
        bfh[sc] = *(const half8*)&Hh[o];
        bfl[sc] = *(const half8*)&Hl[o];
      }
      for (int sr = 0; sr < 2; sr++)
        for (int sc = 0; sc < 8; sc++) {
          acc[sr][sc] = __builtin_amdgcn_mfma_f32_16x16x32_f16(afh[sr], bfh[sc], acc[sr][sc], 0, 0, 0);
          acc[sr][sc] = __builtin_amdgcn_mfma_f32_16x16x32_f16(afh[sr], bfl[sc], acc[sr][sc], 0, 0, 0);
          acc[sr][sc] = __builtin_amdgcn_mfma_f32_16x16x32_f16(afl[sr], bfh[sc], acc[sr][sc], 0, 0, 0);
        }
    }
    __syncthreads();
  }
  float bah[8];
  for (int sc = 0; sc < 8; sc++) bah[sc] = b_ah[sc*16 + l16];
  float* ab = a32 + (size_t)b * NN * HH;
#pragma unroll
  for (int sr = 0; sr < 2; sr++)
    for (int rg = 0; rg < 4; rg++) {
      const int row = n0 + w*32 + sr*16 + quad*4 + rg;   // C/D: row=quad*4+reg
      for (int sc = 0; sc < 8; sc++)
        ab[(size_t)row*HH + sc*16 + l16] = acc[sr][sc][rg] + bah[sc];  // col=lane&15
    }
}

// gates, 128 rows of [B*N] per block (512 blocks), 256 thr = 4 waves, each wave
// owns 32 rows (sr=2 x 16). All GEMMs hi/lo-split f16 MFMA (3 passes), weights
// pre-scaled x16 (epilogue /16). h fp32 in d_out; a fp32 in ws.
// Pass 1: r+z MERGED (shared a/h fragments; 8 weight loads feed 24 MFMAs per sc
// -> 2x latency cover vs split sweeps). Pass 2: c = a@Wc^T + rh@Uc^T.
// rh LDS region is wave-private -> no barrier, only lgkmcnt drain.
// LDS 69.6KB -> 2 blocks/CU (2 waves/SIMD); VGPR budget 256 for that occupancy.
__global__ __launch_bounds__(256, 2) void k_gates(const float* __restrict__ a32,
                                                  float* __restrict__ h,
                                                  const f16* __restrict__ whi,
                                                  const f16* __restrict__ wlo,
                                                  const float* __restrict__ bias3) {
  __shared__ __align__(16) f16 rhh[128*136], rhl[128*136];
  const int row0 = blockIdx.x << 7, tid = threadIdx.x;
  const int w = tid >> 6, L = tid & 63, quad = L >> 4, l16 = L & 15;
  const float* ap[2]; const float* hp[2];
  for (int sr = 0; sr < 2; sr++) {
    int r = row0 + w*32 + sr*16 + l16;
    ap[sr] = a32 + (size_t)r * HH;
    hp[sr] = h + (size_t)r * HH;
  }
  // a fragments (live across both passes): A-op layout m=lane&15, k=quad*8+j
  half8 afh[2][4], afl[2][4];
#pragma unroll
  for (int sr = 0; sr < 2; sr++)
#pragma unroll
    for (int ks = 0; ks < 4; ks++) {
      const int ko = ks*32 + quad*8;
      float4 p = *(const float4*)(ap[sr] + ko);
      float4 q2 = *(const float4*)(ap[sr] + ko + 4);
      const float* v = (const float*)&p;
      const float* v2 = (const float*)&q2;
      for (int i = 0; i < 4; i++) { f16 hi, lo; split1(v[i],  hi, lo); afh[sr][ks][i]   = hi; afl[sr][ks][i]   = lo; }
      for (int i = 0; i < 4; i++) { f16 hi, lo; split1(v2[i], hi, lo); afh[sr][ks][i+4] = hi; afl[sr][ks][i+4] = lo; }
    }
  const floatx4 zero = {0.f, 0.f, 0.f, 0.f};
  const f16* Wz_h = whi;            const f16* Wz_l = wlo;
  const f16* Uz_h = whi + 16384;    const f16* Uz_l = wlo + 16384;
  const f16* Wr_h = whi + 2*16384;  const f16* Wr_l = wlo + 2*16384;
  const f16* Ur_h = whi + 3*16384;  const f16* Ur_l = wlo + 3*16384;
  const f16* Wc_h = whi + 4*16384;  const f16* Wc_l = wlo + 4*16384;
  const f16* Uc_h = whi + 5*16384;  const f16* Uc_l = wlo + 5*16384;

  // ---- pass 1: r + z merged ----
  floatx4 racc[2][8], zacc[2][8];
  for (int sr = 0; sr < 2; sr++)
    for (int sc = 0; sc < 8; sc++) { racc[sr][sc] = zero; zacc[sr][sc] = zero; }
#pragma unroll
  for (int ks = 0; ks < 4; ks++) {
    const int ko = ks*32 + quad*8;
    half8 hfh[2], hfl[2];
    for (int sr = 0; sr < 2; sr++) {
      float4 p = *(const float4*)(hp[sr] + ko);
      float4 q2 = *(const float4*)(hp[sr] + ko + 4);
      const float* v = (const float*)&p; const float* v2 = (const float*)&q2;
      for (int i = 0; i < 4; i++) { f16 hi, lo; split1(v[i],  hi, lo); hfh[sr][i]   = hi; hfl[sr][i]   = lo; }
      for (int i = 0; i < 4; i++) { f16 hi, lo; split1(v2[i], hi, lo); hfh[sr][i+4] = hi; hfl[sr][i+4] = lo; }
    }
#pragma unroll
    for (int sc = 0; sc < 8; sc++) {
      const int wo = (sc*16 + l16)*HH + ko;      // B-op: n=lane&15 row of W, k-contig
      half8 wrh = *(const half8*)(Wr_h + wo), wrl = *(const half8*)(Wr_l + wo);
      half8 urh = *(const half8*)(Ur_h + wo), url = *(const half8*)(Ur_l + wo);
      half8 wzh = *(const half8*)(Wz_h + wo), wzl = *(const half8*)(Wz_l + wo);
      half8 uzh = *(const half8*)(Uz_h + wo), uzl = *(const half8*)(Uz_l + wo);
      for (int sr = 0; sr < 2; sr++) {
        racc[sr][sc] = __builtin_amdgcn_mfma_f32_16x16x32_f16(afh[sr][ks], wrh, racc[sr][sc], 0, 0, 0);
        racc[sr][sc] = __builtin_amdgcn_mfma_f32_16x16x32_f16(afh[sr][ks], wrl, racc[sr][sc], 0, 0, 0);
        racc[sr][sc] = __builtin_amdgcn_mfma_f32_16x16x32_f16(afl[sr][ks], wrh, racc[sr][sc], 0, 0, 0);
        racc[sr][sc] = __builtin_amdgcn_mfma_f32_16x16x32_f16(hfh[sr], urh, racc[sr][sc], 0, 0, 0);
        racc[sr][sc] = __builtin_amdgcn_mfma_f32_16x16x32_f16(hfh[sr], url, racc[sr][sc], 0, 0, 0);
        racc[sr][sc] = __builtin_amdgcn_mfma_f32_16x16x32_f16(hfl[sr], urh, racc[sr][sc], 0, 0, 0);
        zacc[sr][sc] = __builtin_amdgcn_mfma_f32_16x16x32_f16(afh[sr][ks], wzh, zacc[sr][sc], 0, 0, 0);
        zacc[sr][sc] = __builtin_amdgcn_mfma_f32_16x16x32_f16(afh[sr][ks], wzl, zacc[sr][sc], 0, 0, 0);
        zacc[sr][sc] = __builtin_amdgcn_mfma_f32_16x16x32_f16(afl[sr][ks], wzh, zacc[sr][sc], 0, 0, 0);
        zacc[sr][sc] = __builtin_amdgcn_mfma_f32_16x16x32_f16(hfh[sr], uzh, zacc[sr][sc], 0, 0, 0);
        zacc[sr][sc] = __builtin_amdgcn_mfma_f32_16x16x32_f16(hfh[sr], uzl, zacc[sr][sc], 0, 0, 0);
        zacc[sr][sc] = __builtin_amdgcn_mfma_f32_16x16x32_f16(hfl[sr], uzh, zacc[sr][sc], 0, 0, 0);
      }
    }
  }
  // epilogue r: rh = sigmoid(pr)*h -> per-wave LDS region (C/D row=quad*4+reg)
  {
    float brv[8];
    for (int sc = 0; sc < 8; sc++) brv[sc] = bias3[128 + sc*16 + l16];
#pragma unroll
    for (int sr = 0; sr < 2; sr++)
#pragma unroll
      for (int rg = 0; rg < 4; rg++) {
        const int lrow = w*32 + sr*16 + quad*4 + rg;
        const float* hrow = h + (size_t)(row0 + lrow)*HH;
        for (int sc = 0; sc < 8; sc++) {
          const int col = sc*16 + l16;
          float pr = racc[sr][sc][rg] * 0.0625f + brv[sc];
          float rv = 1.f / (1.f + expf(-pr));
          float rhv = rv * hrow[col];
          f16 hi, lo; split1(rhv, hi, lo);
          rhh[lrow*136 + col] = hi;
          rhl[lrow*136 + col] = lo;
        }
      }
  }
  // rh region is wave-private: drain LDS writes, no block barrier
  asm volatile("s_waitcnt lgkmcnt(0)" ::: "memory");

  // ---- pass 2: c = a@Wc^T + rh@Uc^T ----
  floatx4 cacc[2][8];
  for (int sr = 0; sr < 2; sr++) for (int sc = 0; sc < 8; sc++) cacc[sr][sc] = zero;
#pragma unroll
  for (int ks = 0; ks < 4; ks++) {
    const int ko = ks*32 + quad*8;
    half8 rfh[2], rfl[2];
    for (int sr = 0; sr < 2; sr++) {
      int o = (w*32 + sr*16 + l16)*136 + ko;
      rfh[sr] = *(const half8*)&rhh[o];
      rfl[sr] = *(const half8*)&rhl[o];
    }
#pragma unroll
    for (int sc = 0; sc < 8; sc++) {
      const int wo = (sc*16 + l16)*HH + ko;
      half8 wh = *(const half8*)(Wc_h + wo), wl = *(const half8*)(Wc_l + wo);
      half8 uh = *(const half8*)(Uc_h + wo), ul = *(const half8*)(Uc_l + wo);
      for (int sr = 0; sr < 2; sr++) {
        cacc[sr][sc] = __builtin_amdgcn_mfma_f32_16x16x32_f16(afh[sr][ks], wh, cacc[sr][sc], 0, 0, 0);
        cacc[sr][sc] = __builtin_amdgcn_mfma_f32_16x16x32_f16(afh[sr][ks], wl, cacc[sr][sc], 0, 0, 0);
        cacc[sr][sc] = __builtin_amdgcn_mfma_f32_16x16x32_f16(afl[sr][ks], wh, cacc[sr][sc], 0, 0, 0);
        cacc[sr][sc] = __builtin_amdgcn_mfma_f32_16x16x32_f16(rfh[sr], uh, cacc[sr][sc], 0, 0, 0);
        cacc[sr][sc] = __builtin_amdgcn_mfma_f32_16x16x32_f16(rfh[sr], ul, cacc[sr][sc], 0, 0, 0);
        cacc[sr][sc] = __builtin_amdgcn_mfma_f32_16x16x32_f16(rfl[sr], uh, cacc[sr][sc], 0, 0, 0);
      }
    }
  }
  // ---- final epilogue ----
  float bzv[8], bcv[8];
  for (int sc = 0; sc < 8; sc++) {
    bzv[sc] = bias3[sc*16 + l16];
    bcv[sc] = bias3[256 + sc*16 + l16];
  }
#pragma unroll
  for (int sr = 0; sr < 2; sr++)
#pragma unroll
    for (int rg = 0; rg < 4; rg++) {
      const int lrow = w*32 + sr*16 + quad*4 + rg;
      float* hrow = h + (size_t)(row0 + lrow)*HH;
      for (int sc = 0; sc < 8; sc++) {
        const int col = sc*16 + l16;
        float pz = zacc[sr][sc][rg] * 0.0625f + bzv[sc];
        float zv = 1.f / (1.f + expf(-pz));
        float cv = tanhf(cacc[sr][sc][rg] * 0.0625f + bcv[sc]);
        float hv = hrow[col];
        hrow[col] = hv + zv*(cv - hv);   // (1-z)h + z*c
      }
    }
}

extern "C" void kernel_launch(void* const* d_in, const int* in_sizes, int n_in,
                              void* d_out, int out_size, void* d_ws, size_t ws_size,
                              hipStream_t stream) {
  const float* A      = (const float*)d_in[0];
  const float* hidden = (const float*)d_in[1];
  const float* b_ah   = (const float*)d_in[2];
  const float* w_z = (const float*)d_in[3];  const float* b_wz = (const float*)d_in[4];
  const float* u_z = (const float*)d_in[5];  const float* b_uz = (const float*)d_in[6];
  const float* w_r = (const float*)d_in[7];  const float* b_wr = (const float*)d_in[8];
  const float* u_r = (const float*)d_in[9];  const float* b_ur = (const float*)d_in[10];
  const float* w   = (const float*)d_in[11]; const float* b_w  = (const float*)d_in[12];
  const float* u   = (const float*)d_in[13]; const float* b_u  = (const float*)d_in[14];

  float* h = (float*)d_out;                       // fp32 h state == output [B,N,H]
  char* ws = (char*)d_ws;
  float* a32  = (float*)ws;                       // 33,554,432 B
  f16*   whi  = (f16*)(ws + 33554432);            // 196,608 B
  f16*   wlo  = (f16*)(ws + 33751040);            // 196,608 B
  float* bias3= (float*)(ws + 33947648);          // 1,536 B   (total ~33.9 MB)

  k_wsplit<<<384, 256, 0, stream>>>(w_z, u_z, w_r, u_r, w, u, whi, wlo);
  k_bsum<<<3, HH, 0, stream>>>(b_wz, b_uz, b_wr, b_ur, b_w, b_u, bias3);
  k_copy_h0<<<8192, 256, 0, stream>>>(hidden, h);

  for (int t = 0; t < TT; t++) {
    k_biggemm<<<dim3(4, BB), 256, 0, stream>>>(A, h, b_ah, a32);
    k_gates<<<512, 256, 0, stream>>>(a32, h, whi, wlo, bias3);
  }
}

// Round 4
// 983.431 us; speedup vs baseline: 1.2200x; 1.0094x over previous
//
#include <hip/hip_runtime.h>
#include <hip/hip_fp16.h>

#define BB 128
#define NN 512
#define HH 128
#define TT 4

typedef _Float16 f16;
typedef _Float16 half8 __attribute__((ext_vector_type(8)));
typedef float floatx4 __attribute__((ext_vector_type(4)));

// fp32 -> f16 hi/lo split: x ~= hi + lo, |lo| <= |x|*2^-11
__device__ __forceinline__ void split1(float x, f16& hi, f16& lo) {
  hi = (f16)x;
  lo = (f16)(x - (float)hi);
}

// ---------- one-time prep ----------

// six HxH fp32 weights, pre-scaled x16, split into f16 hi/lo
__global__ void k_wsplit(const float* __restrict__ wz, const float* __restrict__ uz,
                         const float* __restrict__ wr, const float* __restrict__ ur,
                         const float* __restrict__ wc, const float* __restrict__ uc,
                         f16* __restrict__ whi, f16* __restrict__ wlo) {
  int mat = blockIdx.x >> 6;
  int idx = ((blockIdx.x & 63) << 8) + threadIdx.x;
  const float* src = mat==0?wz : mat==1?uz : mat==2?wr : mat==3?ur : mat==4?wc : uc;
  float v = src[idx] * 16.0f;
  f16 hi, lo; split1(v, hi, lo);
  whi[mat*16384 + idx] = hi;
  wlo[mat*16384 + idx] = lo;
}

// summed gate biases: [0]=b_wz+b_uz, [1]=b_wr+b_ur, [2]=b_w+b_u
__global__ void k_bsum(const float* __restrict__ bwz, const float* __restrict__ buz,
                       const float* __restrict__ bwr, const float* __restrict__ bur,
                       const float* __restrict__ bw,  const float* __restrict__ bu,
                       float* __restrict__ bias3) {
  int b = blockIdx.x, j = threadIdx.x;
  bias3[b*HH + j] = b==0 ? bwz[j]+buz[j] : (b==1 ? bwr[j]+bur[j] : bw[j]+bu[j]);
}

__global__ void k_copy_h0(const float* __restrict__ hin, float* __restrict__ h) {
  int v = blockIdx.x * 256 + threadIdx.x;
  ((float4*)h)[v] = ((const float4*)hin)[v];
}

// ---------- per-step kernels ----------

// a32[b][n][j] = b_ah[j] + sum_m A[b][m][n] * h[b][m][j], fp32-accurate via
// hi/lo split f16 MFMA (3 passes). In-kernel transpose staging, XOR-swizzled.
// grid (4 n-tiles, 128 batch), 256 thr (4 waves), tile 128x128, BK=64.
__global__ __launch_bounds__(256) void k_biggemm(const float* __restrict__ A,
                                                 const float* __restrict__ h,
                                                 const float* __restrict__ b_ah,
                                                 float* __restrict__ a32) {
  __shared__ __align__(16) f16 Ah[128*64], Al[128*64], Hh[128*64], Hl[128*64];
  const int b = blockIdx.y, n0 = blockIdx.x * 128, tid = threadIdx.x;
  const int w = tid >> 6, L = tid & 63, quad = L >> 4, l16 = L & 15;
  const int rowsel = tid >> 5, colsel = tid & 31;
  const float* Ab = A + (size_t)b * NN * NN;
  const float* hb = h + (size_t)b * NN * HH;
  const floatx4 zero = {0.f, 0.f, 0.f, 0.f};
  floatx4 acc[2][8];
  for (int sr = 0; sr < 2; sr++) for (int sc = 0; sc < 8; sc++) acc[sr][sc] = zero;

  for (int mc = 0; mc < NN; mc += 64) {
    float4 va[8], vh[8];
#pragma unroll
    for (int i = 0; i < 8; i++) {
      int mm = rowsel * 8 + i;
      va[i] = *(const float4*)(Ab + (size_t)(mc + mm) * NN + n0 + colsel * 4);
      vh[i] = *(const float4*)(hb + (size_t)(mc + mm) * HH + colsel * 4);
    }
#pragma unroll
    for (int q = 0; q < 4; q++) {
      int c = colsel * 4 + q;
      half8 avh, avl, hvh, hvl;
#pragma unroll
      for (int i = 0; i < 8; i++) {
        f16 hi, lo;
        split1(((const float*)&va[i])[q], hi, lo); avh[i] = hi; avl[i] = lo;
        split1(((const float*)&vh[i])[q], hi, lo); hvh[i] = hi; hvl[i] = lo;
      }
      int blk = (rowsel ^ (c & 7)) * 8;
      *(half8*)&Ah[c*64 + blk] = avh;  *(half8*)&Al[c*64 + blk] = avl;
      *(half8*)&Hh[c*64 + blk] = hvh;  *(half8*)&Hl[c*64 + blk] = hvl;
    }
    __syncthreads();
#pragma unroll
    for (int ks = 0; ks < 2; ks++) {
      const int kb = ks * 4 + quad;
      half8 afh[2], afl[2], bfh[8], bfl[8];
      for (int sr = 0; sr < 2; sr++) {
        int c = w*32 + sr*16 + l16, o = c*64 + ((kb ^ (c & 7)) * 8);
        afh[sr] = *(const half8*)&Ah[o];
        afl[sr] = *(const half8*)&Al[o];
      }
      for (int sc = 0; sc < 8; sc++) {
        int c = sc*16 + l16, o = c*64 + ((kb ^ (c & 7)) * 8);
        bfh[sc] = *(const half8*)&Hh[o];
        bfl[sc] = *(const half8*)&Hl[o];
      }
      for (int sr = 0; sr < 2; sr++)
        for (int sc = 0; sc < 8; sc++) {
          acc[sr][sc] = __builtin_amdgcn_mfma_f32_16x16x32_f16(afh[sr], bfh[sc], acc[sr][sc], 0, 0, 0);
          acc[sr][sc] = __builtin_amdgcn_mfma_f32_16x16x32_f16(afh[sr], bfl[sc], acc[sr][sc], 0, 0, 0);
          acc[sr][sc] = __builtin_amdgcn_mfma_f32_16x16x32_f16(afl[sr], bfh[sc], acc[sr][sc], 0, 0, 0);
        }
    }
    __syncthreads();
  }
  float bah[8];
  for (int sc = 0; sc < 8; sc++) bah[sc] = b_ah[sc*16 + l16];
  float* ab = a32 + (size_t)b * NN * HH;
#pragma unroll
  for (int sr = 0; sr < 2; sr++)
    for (int rg = 0; rg < 4; rg++) {
      const int row = n0 + w*32 + sr*16 + quad*4 + rg;   // C/D: row=quad*4+reg
      for (int sc = 0; sc < 8; sc++)
        ab[(size_t)row*HH + sc*16 + l16] = acc[sr][sc][rg] + bah[sc];  // col=lane&15
    }
}

// gates, 128 rows of [B*N] per block (512 blocks), 256 thr = 4 waves, each wave
// owns 32 rows (sr=2 x 16). All GEMMs hi/lo-split f16 MFMA (3 passes), weights
// pre-scaled x16 (epilogue /16).
// SC-TILED so no gate accumulator array persists (round-2 spill fix), and
// a/h fragments BOTH loaded persistently up front (round-3 RAW fix: pass-2
// epilogue writes h, so no h re-read may occur after the first stripe update).
//   P1: r gate, sc-tile=4 -> rh (hi/lo) to wave-private LDS.
//   P2: z+c merged, sc-tile=2, rh from LDS per (tile,ks), fused per-stripe
//       h-update epilogue (h written exactly once per element, never re-read
//       as GEMM operand -- operands live in registers).
__global__ __launch_bounds__(256, 2) void k_gates(const float* __restrict__ a32,
                                                  float* __restrict__ h,
                                                  const f16* __restrict__ whi,
                                                  const f16* __restrict__ wlo,
                                                  const float* __restrict__ bias3) {
  __shared__ __align__(16) f16 rhh[128*136], rhl[128*136];
  const int row0 = blockIdx.x << 7, tid = threadIdx.x;
  const int w = tid >> 6, L = tid & 63, quad = L >> 4, l16 = L & 15;
  const float* ap[2]; const float* hp[2];
  for (int sr = 0; sr < 2; sr++) {
    int r = row0 + w*32 + sr*16 + l16;
    ap[sr] = a32 + (size_t)r * HH;
    hp[sr] = h + (size_t)r * HH;
  }
  // persistent fragments (A-op layout m=lane&15, k=quad*8+j): a and h, hi/lo
  half8 afh[2][4], afl[2][4], hfh[2][4], hfl[2][4];
#pragma unroll
  for (int sr = 0; sr < 2; sr++)
#pragma unroll
    for (int ks = 0; ks < 4; ks++) {
      const int ko = ks*32 + quad*8;
      float4 p = *(const float4*)(ap[sr] + ko);
      float4 q2 = *(const float4*)(ap[sr] + ko + 4);
      const float* v = (const float*)&p;
      const float* v2 = (const float*)&q2;
      for (int i = 0; i < 4; i++) { f16 hi, lo; split1(v[i],  hi, lo); afh[sr][ks][i]   = hi; afl[sr][ks][i]   = lo; }
      for (int i = 0; i < 4; i++) { f16 hi, lo; split1(v2[i], hi, lo); afh[sr][ks][i+4] = hi; afl[sr][ks][i+4] = lo; }
      float4 hpv = *(const float4*)(hp[sr] + ko);
      float4 hqv = *(const float4*)(hp[sr] + ko + 4);
      const float* hv1 = (const float*)&hpv;
      const float* hv2 = (const float*)&hqv;
      for (int i = 0; i < 4; i++) { f16 hi, lo; split1(hv1[i], hi, lo); hfh[sr][ks][i]   = hi; hfl[sr][ks][i]   = lo; }
      for (int i = 0; i < 4; i++) { f16 hi, lo; split1(hv2[i], hi, lo); hfh[sr][ks][i+4] = hi; hfl[sr][ks][i+4] = lo; }
    }
  const floatx4 zero = {0.f, 0.f, 0.f, 0.f};
  const f16* Wz_h = whi;            const f16* Wz_l = wlo;
  const f16* Uz_h = whi + 16384;    const f16* Uz_l = wlo + 16384;
  const f16* Wr_h = whi + 2*16384;  const f16* Wr_l = wlo + 2*16384;
  const f16* Ur_h = whi + 3*16384;  const f16* Ur_l = wlo + 3*16384;
  const f16* Wc_h = whi + 4*16384;  const f16* Wc_l = wlo + 4*16384;
  const f16* Uc_h = whi + 5*16384;  const f16* Uc_l = wlo + 5*16384;

  // ---- Pass 1: r gate, sc tiles of 4 ----
#pragma unroll 1
  for (int scT = 0; scT < 2; scT++) {
    floatx4 racc[2][4];
    for (int sr = 0; sr < 2; sr++) for (int si = 0; si < 4; si++) racc[sr][si] = zero;
#pragma unroll
    for (int ks = 0; ks < 4; ks++) {
      const int ko = ks*32 + quad*8;
#pragma unroll
      for (int si = 0; si < 4; si++) {
        const int wo = ((scT*4 + si)*16 + l16)*HH + ko;   // B-op: n-row of W, k-contig
        half8 wh = *(const half8*)(Wr_h + wo), wl = *(const half8*)(Wr_l + wo);
        half8 uh = *(const half8*)(Ur_h + wo), ul = *(const half8*)(Ur_l + wo);
#pragma unroll
        for (int sr = 0; sr < 2; sr++) {
          racc[sr][si] = __builtin_amdgcn_mfma_f32_16x16x32_f16(afh[sr][ks], wh, racc[sr][si], 0, 0, 0);
          racc[sr][si] = __builtin_amdgcn_mfma_f32_16x16x32_f16(afh[sr][ks], wl, racc[sr][si], 0, 0, 0);
          racc[sr][si] = __builtin_amdgcn_mfma_f32_16x16x32_f16(afl[sr][ks], wh, racc[sr][si], 0, 0, 0);
          racc[sr][si] = __builtin_amdgcn_mfma_f32_16x16x32_f16(hfh[sr][ks], uh, racc[sr][si], 0, 0, 0);
          racc[sr][si] = __builtin_amdgcn_mfma_f32_16x16x32_f16(hfh[sr][ks], ul, racc[sr][si], 0, 0, 0);
          racc[sr][si] = __builtin_amdgcn_mfma_f32_16x16x32_f16(hfl[sr][ks], uh, racc[sr][si], 0, 0, 0);
        }
      }
    }
    // per-tile epilogue: rh = sigmoid(pr)*h -> wave-private LDS (hi/lo)
#pragma unroll
    for (int si = 0; si < 4; si++) {
      const int col = (scT*4 + si)*16 + l16;
      const float brv = bias3[128 + col];
#pragma unroll
      for (int sr = 0; sr < 2; sr++)
#pragma unroll
        for (int rg = 0; rg < 4; rg++) {
          const int lrow = w*32 + sr*16 + quad*4 + rg;    // C/D: row=quad*4+reg
          const float* hrow = h + (size_t)(row0 + lrow)*HH;
          float pr = racc[sr][si][rg] * 0.0625f + brv;
          float rv = 1.f / (1.f + expf(-pr));
          float rhv = rv * hrow[col];
          f16 hi, lo; split1(rhv, hi, lo);
          rhh[lrow*136 + col] = hi;
          rhl[lrow*136 + col] = lo;
        }
    }
  }
  // rh region is wave-private: drain LDS writes, no block barrier
  asm volatile("s_waitcnt lgkmcnt(0)" ::: "memory");

  // ---- Pass 2: z + c merged, sc tiles of 2, fused h-update epilogue ----
#pragma unroll 1
  for (int scT = 0; scT < 4; scT++) {
    floatx4 zacc[2][2], cacc[2][2];
    for (int sr = 0; sr < 2; sr++)
      for (int si = 0; si < 2; si++) { zacc[sr][si] = zero; cacc[sr][si] = zero; }
#pragma unroll
    for (int ks = 0; ks < 4; ks++) {
      const int ko = ks*32 + quad*8;
      half8 rfh[2], rfl[2];
#pragma unroll
      for (int sr = 0; sr < 2; sr++) {
        int o = (w*32 + sr*16 + l16)*136 + ko;
        rfh[sr] = *(const half8*)&rhh[o];
        rfl[sr] = *(const half8*)&rhl[o];
      }
#pragma unroll
      for (int si = 0; si < 2; si++) {
        const int wo = ((scT*2 + si)*16 + l16)*HH + ko;
        half8 wzh = *(const half8*)(Wz_h + wo), wzl = *(const half8*)(Wz_l + wo);
        half8 uzh = *(const half8*)(Uz_h + wo), uzl = *(const half8*)(Uz_l + wo);
        half8 wch = *(const half8*)(Wc_h + wo), wcl = *(const half8*)(Wc_l + wo);
        half8 uch = *(const half8*)(Uc_h + wo), ucl = *(const half8*)(Uc_l + wo);
#pragma unroll
        for (int sr = 0; sr < 2; sr++) {
          zacc[sr][si] = __builtin_amdgcn_mfma_f32_16x16x32_f16(afh[sr][ks], wzh, zacc[sr][si], 0, 0, 0);
          zacc[sr][si] = __builtin_amdgcn_mfma_f32_16x16x32_f16(afh[sr][ks], wzl, zacc[sr][si], 0, 0, 0);
          zacc[sr][si] = __builtin_amdgcn_mfma_f32_16x16x32_f16(afl[sr][ks], wzh, zacc[sr][si], 0, 0, 0);
          zacc[sr][si] = __builtin_amdgcn_mfma_f32_16x16x32_f16(hfh[sr][ks], uzh, zacc[sr][si], 0, 0, 0);
          zacc[sr][si] = __builtin_amdgcn_mfma_f32_16x16x32_f16(hfh[sr][ks], uzl, zacc[sr][si], 0, 0, 0);
          zacc[sr][si] = __builtin_amdgcn_mfma_f32_16x16x32_f16(hfl[sr][ks], uzh, zacc[sr][si], 0, 0, 0);
          cacc[sr][si] = __builtin_amdgcn_mfma_f32_16x16x32_f16(afh[sr][ks], wch, cacc[sr][si], 0, 0, 0);
          cacc[sr][si] = __builtin_amdgcn_mfma_f32_16x16x32_f16(afh[sr][ks], wcl, cacc[sr][si], 0, 0, 0);
          cacc[sr][si] = __builtin_amdgcn_mfma_f32_16x16x32_f16(afl[sr][ks], wch, cacc[sr][si], 0, 0, 0);
          cacc[sr][si] = __builtin_amdgcn_mfma_f32_16x16x32_f16(rfh[sr], uch, cacc[sr][si], 0, 0, 0);
          cacc[sr][si] = __builtin_amdgcn_mfma_f32_16x16x32_f16(rfh[sr], ucl, cacc[sr][si], 0, 0, 0);
          cacc[sr][si] = __builtin_amdgcn_mfma_f32_16x16x32_f16(rfl[sr], uch, cacc[sr][si], 0, 0, 0);
        }
      }
    }
    // fused final epilogue for this 32-col stripe (h written once, never re-read)
#pragma unroll
    for (int si = 0; si < 2; si++) {
      const int col = (scT*2 + si)*16 + l16;
      const float bzv = bias3[col];
      const float bcv = bias3[256 + col];
#pragma unroll
      for (int sr = 0; sr < 2; sr++)
#pragma unroll
        for (int rg = 0; rg < 4; rg++) {
          const int lrow = w*32 + sr*16 + quad*4 + rg;
          float* hrow = h + (size_t)(row0 + lrow)*HH;
          float pz = zacc[sr][si][rg] * 0.0625f + bzv;
          float zv = 1.f / (1.f + expf(-pz));
          float cv = tanhf(cacc[sr][si][rg] * 0.0625f + bcv);
          float hv = hrow[col];
          hrow[col] = hv + zv*(cv - hv);   // (1-z)h + z*c
        }
    }
  }
}

extern "C" void kernel_launch(void* const* d_in, const int* in_sizes, int n_in,
                              void* d_out, int out_size, void* d_ws, size_t ws_size,
                              hipStream_t stream) {
  const float* A      = (const float*)d_in[0];
  const float* hidden = (const float*)d_in[1];
  const float* b_ah   = (const float*)d_in[2];
  const float* w_z = (const float*)d_in[3];  const float* b_wz = (const float*)d_in[4];
  const float* u_z = (const float*)d_in[5];  const float* b_uz = (const float*)d_in[6];
  const float* w_r = (const float*)d_in[7];  const float* b_wr = (const float*)d_in[8];
  const float* u_r = (const float*)d_in[9];  const float* b_ur = (const float*)d_in[10];
  const float* w   = (const float*)d_in[11]; const float* b_w  = (const float*)d_in[12];
  const float* u   = (const float*)d_in[13]; const float* b_u  = (const float*)d_in[14];

  float* h = (float*)d_out;                       // fp32 h state == output [B,N,H]
  char* ws = (char*)d_ws;
  float* a32  = (float*)ws;                       // 33,554,432 B
  f16*   whi  = (f16*)(ws + 33554432);            // 196,608 B
  f16*   wlo  = (f16*)(ws + 33751040);            // 196,608 B
  float* bias3= (float*)(ws + 33947648);          // 1,536 B   (total ~33.9 MB)

  k_wsplit<<<384, 256, 0, stream>>>(w_z, u_z, w_r, u_r, w, u, whi, wlo);
  k_bsum<<<3, HH, 0, stream>>>(b_wz, b_uz, b_wr, b_ur, b_w, b_u, bias3);
  k_copy_h0<<<8192, 256, 0, stream>>>(hidden, h);

  for (int t = 0; t < TT; t++) {
    k_biggemm<<<dim3(4, BB), 256, 0, stream>>>(A, h, b_ah, a32);
    k_gates<<<512, 256, 0, stream>>>(a32, h, whi, wlo, bias3);
  }
}